// Round 10
// baseline (58.819 us; speedup 1.0000x reference)
//
#include <hip/hip_runtime.h>
#include <stdint.h>

// Problem constants
#define B_  32
#define S_  512
#define C_  320
#define H_  512

typedef __attribute__((ext_vector_type(8))) short short8;
typedef __attribute__((ext_vector_type(4))) float f32x4;

__device__ __forceinline__ unsigned short f2bf(float x){
  unsigned u = __builtin_bit_cast(unsigned, x);
  u = u + 0x7FFFu + ((u >> 16) & 1u);          // round-to-nearest-even
  return (unsigned short)(u >> 16);
}
__device__ __forceinline__ float sigf(float x){ return 1.0f/(1.0f + __expf(-x)); }
__device__ __forceinline__ float tanh_fast(float x){ return 2.0f/(1.0f + __expf(-2.0f*x)) - 1.0f; }

__device__ __forceinline__ void gload16(const void* g, void* l){
  __builtin_amdgcn_global_load_lds((const __attribute__((address_space(1))) void*)g,
                                   (__attribute__((address_space(3))) void*)l, 16, 0, 0);
}

// ---- Pass 0 (fused): blocks 0..767 cast w_ih; blocks 768..2047 cast+T x ----
// x part writes xws2[n'][s], n' = c*32 + b (scramble folded into the layout).
__global__ __launch_bounds__(256) void k_prep(const float* __restrict__ w,
                                              const float* __restrict__ x,
                                              unsigned short* __restrict__ aws,
                                              unsigned short* __restrict__ xws){
  const int bidg = blockIdx.x;
  const int tid = threadIdx.x;
  if (bidg < 768){
    // compact+cast w_ih rows {i:0-511, g:1024-1535, o:1536-2047} -> aws[3][512][512]
    int flat = bidg*256 + tid;                 // float4 units; 3*512*512/4 = 196608
    int plane = flat >> 16;
    int rem   = flat & 65535;
    int srow  = (plane == 0 ? 0 : (plane == 1 ? 1024 : 1536));
    float4 v = ((const float4*)w)[srow*128 + rem];
    uint2 p;
    p.x = (unsigned)f2bf(v.x) | ((unsigned)f2bf(v.y) << 16);
    p.y = (unsigned)f2bf(v.z) | ((unsigned)f2bf(v.w) << 16);
    ((uint2*)aws)[flat] = p;
    return;
  }
  // x (b,s,c) f32 -> xws2[c*32+b][s] bf16 (64x64 LDS transpose tile)
  __shared__ float lds[64][65];
  const int idx = bidg - 768;                  // 0..1279 = st + 8*ctt + 40*b
  const int st = idx & 7;
  const int r5 = idx >> 3;
  const int ctt = r5 % 5, b = r5 / 5;
  const int s0 = st*64, c0 = ctt*64;
  const int row = tid >> 2, q = tid & 3;

  const float* src = x + ((size_t)(b*S_ + s0 + row))*C_ + c0 + q*16;
  #pragma unroll
  for (int j = 0; j < 4; j++){
    float4 v = ((const float4*)src)[j];
    lds[row][q*16 + j*4 + 0] = v.x;
    lds[row][q*16 + j*4 + 1] = v.y;
    lds[row][q*16 + j*4 + 2] = v.z;
    lds[row][q*16 + j*4 + 3] = v.w;
  }
  __syncthreads();
  // write phase (coalesced): 8 lanes cover one n'-row's 64 s-elems (128B run)
  const int wr2 = tid >> 3;                    // 0..31
  const int l8  = tid & 7;
  #pragma unroll
  for (int half = 0; half < 2; half++){
    const int crow = half*32 + wr2;            // 0..63
    const size_t nprime = (size_t)(c0 + crow)*32 + (size_t)b;
    short8 o;
    #pragma unroll
    for (int e = 0; e < 8; e++)
      o[e] = (short)f2bf(lds[l8*8 + e][crow]);
    *(short8*)(xws + nprime*S_ + s0 + l8*8) = o;
  }
}

// ---- Pass 1: monolithic-K MFMA GEMM + LSTM epilogue + fused out ------------
// GEMM: M=1536 (3g x 512k), N=10240 (n' = c*32+b), K=512 in ONE shot.
// Tile BM=96 (3 gates x 32 k) x BN=64 x BK=512: A 96KB + B 64KB = 160KB LDS
// staged ONCE per block (one vmcnt drain + one barrier, vs 16 barriers in
// the K-looped structure that pinned every prior variant at ~350 TF).
// Grid 2560 = 16 mt x 160 nt = 10 rounds of 1 block/CU; 4 waves (2M x 2N).
// Staging: chunk = 1 full 1024B row; source pre-swizzled (lane*16)^((row&7)<<4)
// -> ds_read_b128 fragment reads are 2-way (free) bank-aliased.
__global__ __launch_bounds__(256) void k_gemm(const unsigned short* __restrict__ aws,
                                              const unsigned short* __restrict__ xws,
                                              const float* __restrict__ b_ih,
                                              const float* __restrict__ b_hh,
                                              float* __restrict__ out){
  // A [3][32 rows][1024B] at 0..98304; B [64 rows][1024B] at 98304..163840
  __shared__ alignas(16) char lds[163840];

  const int tid  = threadIdx.x;
  const int w    = tid >> 6;
  const int lane = tid & 63;
  const int wm = w >> 1, wn = w & 1;

  // decode: x8 = XCD; per XCD walk mt fastest at fixed nt (A-slice tiny; the
  // 16 mt-blocks sharing a B-slice land on one XCD -> B L2 reuse). 160=20*8.
  const int bid = blockIdx.x;                  // 0..2559
  const int x8 = bid & 7, y = bid >> 3;        // y 0..319
  const int mt = y & 15, g = y >> 4;           // g 0..19
  const int nt = g*8 + x8;                     // 0..159
  const int k0 = mt*32;
  const int nbase = nt*64;

  f32x4 acc[3][2];
  #pragma unroll
  for (int gi = 0; gi < 3; gi++)
    #pragma unroll
    for (int nf = 0; nf < 2; nf++)
      acc[gi][nf] = (f32x4){0.f, 0.f, 0.f, 0.f};

  // ---- stage all 160 KB: 160 row-chunks, i*4+w split => A/B compile-time ----
  const char* wsb = (const char*)aws;
  {
    // A chunks: q = i*4+w, i 0..23 -> q 0..95: gi = q>>5, row = q&31
    #pragma unroll
    for (int i = 0; i < 24; i++){
      const int q = i*4 + w;
      const int gi = q >> 5, row = q & 31;
      const int slot = (lane << 4) ^ ((row & 7) << 4);
      const unsigned src = (unsigned)((gi*512 + k0 + row)*1024) + (unsigned)slot;
      gload16(wsb + (size_t)src, &lds[0] + gi*32768 + row*1024);
    }
    // B chunks: i 24..39 -> row = (i-24)*4 + w, 0..63
    #pragma unroll
    for (int i = 0; i < 16; i++){
      const int row = i*4 + w;
      const int slot = (lane << 4) ^ ((row & 7) << 4);
      const unsigned src = 2097152u + (unsigned)((nbase + row)*1024) + (unsigned)slot;
      gload16(wsb + (size_t)src, &lds[0] + 98304 + row*1024);
    }
  }
  __syncthreads();                             // ONE drain+barrier per block

  // ---- compute: 16 ks steps x (5 ds_read_b128 + 6 MFMA) per wave ----
  const int l15  = lane & 15;
  const int hi16 = (lane >> 4) << 4;           // lane's 16B within the 64B k-span
  const int xkey = (l15 & 7) << 4;
  const int arow = wm*16 + l15;                // A local row 0..31
  const int brow0 = wn*32 + l15;               // B local row base (+nf*16)

  #pragma unroll
  for (int ks = 0; ks < 16; ks++){
    const int colb = (ks*64 + hi16) ^ xkey;
    short8 aF[3], bF[2];
    #pragma unroll
    for (int gi = 0; gi < 3; gi++)
      aF[gi] = *(const short8*)(&lds[0] + gi*32768 + arow*1024 + colb);
    #pragma unroll
    for (int nf = 0; nf < 2; nf++)
      bF[nf] = *(const short8*)(&lds[0] + 98304 + (brow0 + nf*16)*1024 + colb);
    #pragma unroll
    for (int gi = 0; gi < 3; gi++)
      #pragma unroll
      for (int nf = 0; nf < 2; nf++)
        acc[gi][nf] = __builtin_amdgcn_mfma_f32_16x16x32_bf16(aF[gi], bF[nf], acc[gi][nf], 0, 0, 0);
  }
  __syncthreads();                             // all waves done reading LDS

  // ---- epilogue: gates -> h -> tr[32 k][68] f32 (in reused LDS) ----
  float* tr = (float*)&lds[0];
  {
    const int kbl = wm*16 + ((lane >> 4) << 2);     // local k, + r (0..31)
    const int kg  = k0 + kbl;
    float bi[4], bg[4], bo[4];
    #pragma unroll
    for (int r = 0; r < 4; r++){
      bi[r] = b_ih[kg + r]        + b_hh[kg + r];
      bg[r] = b_ih[1024 + kg + r] + b_hh[1024 + kg + r];
      bo[r] = b_ih[1536 + kg + r] + b_hh[1536 + kg + r];
    }
    #pragma unroll
    for (int nf = 0; nf < 2; nf++){
      const int nl = wn*32 + nf*16 + l15;           // local n' 0..63
      #pragma unroll
      for (int r = 0; r < 4; r++){
        float iv = acc[0][nf][r] + bi[r];
        float gv = acc[1][nf][r] + bg[r];
        float ov = acc[2][nf][r] + bo[r];
        float ce = sigf(iv) * tanh_fast(gv);
        tr[(kbl + r)*68 + nl] = sigf(ov) * tanh_fast(ce);
      }
    }
  }
  __syncthreads();

  // ---- store: fully coalesced. Thread t: k-row = t>>3, 8 lanes cover 32
  // consecutive n' (128B run) per j; 64-run never crosses a b2 boundary
  // (nbase%320 in {0,64,128,192,256}; 256+64=320).
  const int klo   = tid >> 3;                  // 0..31
  const int lane8 = tid & 7;
  const size_t rowoff = (size_t)(k0 + klo)*C_;
  #pragma unroll
  for (int j = 0; j < 2; j++){
    const int nl0 = j*32 + lane8*4;
    const int ng  = nbase + nl0;               // global n' = b2*320 + c2
    const int b2  = ng / 320;                  // const-div -> magic mul
    const int c2  = ng - b2*320;
    float4 v;
    v.x = tr[klo*68 + nl0 + 0];
    v.y = tr[klo*68 + nl0 + 1];
    v.z = tr[klo*68 + nl0 + 2];
    v.w = tr[klo*68 + nl0 + 3];
    *(float4*)(out + (size_t)b2*(H_*C_) + rowoff + c2) = v;
  }
}

extern "C" void kernel_launch(void* const* d_in, const int* in_sizes, int n_in,
                              void* d_out, int out_size, void* d_ws, size_t ws_size,
                              hipStream_t stream){
  const float* x    = (const float*)d_in[0];
  const float* w_ih = (const float*)d_in[1];
  // d_in[2] = w_hh is mathematically dead (h0 = 0)
  const float* b_ih = (const float*)d_in[3];
  const float* b_hh = (const float*)d_in[4];
  float* out = (float*)d_out;

  char* ws = (char*)d_ws;
  unsigned short* aws = (unsigned short*)(ws);                           // 1.5 MiB (3*512*512 bf16)
  unsigned short* xws = (unsigned short*)(ws + 2097152);                 // 10 MiB  (10240*512 bf16, n'-layout)
  // total workspace use: ~12 MiB

  k_prep <<<2048, 256, 0, stream>>>(w_ih, x, aws, xws);
  k_gemm <<<2560, 256, 0, stream>>>(aws, xws, b_ih, b_hh, out);
}